// Round 5
// baseline (1557.556 us; speedup 1.0000x reference)
//
#include <hip/hip_runtime.h>

#define NROWS 16384
#define DIM   512
#define KC    8192
#define BM    64
#define NT    128            // K tiles of 64 codes
#define QCAP  32768
#define MARGIN 0.05f
#define DEFER_THR 8.0f
#define LN2   0.69314718055994531f

typedef _Float16 half8  __attribute__((ext_vector_type(8)));
typedef float    f32x4  __attribute__((ext_vector_type(4)));
typedef unsigned int u32;

#define MFMA(a,b,c) __builtin_amdgcn_mfma_f32_16x16x32_f16(a,b,c,0,0,0)

__device__ __forceinline__ float flog2(float x){ return __builtin_amdgcn_logf(x); }
__device__ __forceinline__ float fexp2(float x){ return __builtin_amdgcn_exp2f(x); }
__device__ __forceinline__ f32x4 ntload4(const float* p){
  return __builtin_nontemporal_load((const f32x4*)p);
}
__device__ __forceinline__ void gload16(const void* g, void* l){
  __builtin_amdgcn_global_load_lds(
      (const __attribute__((address_space(1))) u32*)g,
      (__attribute__((address_space(3))) u32*)l, 16, 0, 0);
}

__device__ __forceinline__ void top2_merge(float& v1, int& i1, float& v2, int& i2,
                                           float bv1, int bi1, float bv2, int bi2) {
  bool takeB = (bv1 > v1) || (bv1 == v1 && bi1 < i1);
  float nv1 = takeB ? bv1 : v1; int ni1 = takeB ? bi1 : i1;
  float cv  = takeB ? v1  : bv1; int ci = takeB ? i1  : bi1;
  float ov2 = takeB ? bv2 : v2;  int oi = takeB ? bi2 : i2;
  bool cb = (cv > ov2) || (cv == ov2 && ci < oi);
  v2 = cb ? cv : ov2; i2 = cb ? ci : oi;
  v1 = nv1; i1 = ni1;
}

// ---------------- prep kernels (identical to R4) ----------------
__global__ void prep_x(const float* __restrict__ x, _Float16* __restrict__ xh) {
  size_t i = (size_t)(blockIdx.x * blockDim.x + threadIdx.x) * 4;
  f32x4 v = *(const f32x4*)(x + i);
  _Float16 h4[4];
  h4[0] = (_Float16)(2.0f * v[0]); h4[1] = (_Float16)(2.0f * v[1]);
  h4[2] = (_Float16)(2.0f * v[2]); h4[3] = (_Float16)(2.0f * v[3]);
  *(uint2*)(xh + i) = *(uint2*)h4;
}

__global__ void prep_cht(const float* __restrict__ c, _Float16* __restrict__ cht) {
  const int gid = blockIdx.x * 256 + threadIdx.x;
  const int code = gid >> 6, u = gid & 63;
  f32x4 v0 = *(const f32x4*)(c + (size_t)code * DIM + u * 8);
  f32x4 v1 = *(const f32x4*)(c + (size_t)code * DIM + u * 8 + 4);
  half8 h;
#pragma unroll
  for (int q = 0; q < 4; ++q) { h[q] = (_Float16)v0[q]; h[4+q] = (_Float16)v1[q]; }
  const int t = code >> 6, cc = code & 63;
  *(half8*)((char*)cht + (size_t)t * 65536 + cc * 1024 + ((u ^ (cc & 7)) << 4)) = h;
}

__global__ void prep_ctt(const float* __restrict__ c, _Float16* __restrict__ ctt) {
  __shared__ _Float16 lt[64][72];
  const int kb = (blockIdx.x >> 3) * 64;
  const int db = (blockIdx.x & 7) * 64;
  {
    const int r = threadIdx.x >> 2, c4 = threadIdx.x & 3;
#pragma unroll
    for (int j = 0; j < 4; ++j) {
      f32x4 v = *(const f32x4*)(c + (size_t)(kb + r) * DIM + db + c4 * 16 + j * 4);
#pragma unroll
      for (int q = 0; q < 4; ++q) lt[r][c4 * 16 + j * 4 + q] = (_Float16)v[q];
    }
  }
  __syncthreads();
  {
    const int d = threadIdx.x >> 2, ks = threadIdx.x & 3;
    half8 o0, o1;
#pragma unroll
    for (int j = 0; j < 8; ++j) { o0[j] = lt[ks*16 + j][d]; o1[j] = lt[ks*16 + 8 + j][d]; }
    const int t = kb >> 6, dg = db + d;
    char* base = (char*)ctt + (size_t)t * 65536 + (size_t)dg * 128;
    *(half8*)(base + (((ks*2)     ^ (dg & 7)) << 4)) = o0;
    *(half8*)(base + (((ks*2 + 1) ^ (dg & 7)) << 4)) = o1;
  }
}

__global__ void prep_c2(const float* __restrict__ c, float* __restrict__ c2) {
  const int w = threadIdx.x >> 6, l = threadIdx.x & 63;
  const int code = blockIdx.x * 4 + w;
  double s = 0.0;
  for (int i = l; i < DIM; i += 64) { double v = c[(size_t)code * DIM + i]; s += v * v; }
#pragma unroll
  for (int o = 32; o; o >>= 1) s += __shfl_down(s, o, 64);
  if (l == 0) c2[code] = (float)s;
}

// ---------------- main fused kernel ----------------
// Same math/layout as R4. Schedule change: ONE barrier per tile (mtab dbuf'd),
// static phase indexing via 2-unrolled body, U prefetch post-barrier 2 tiles ahead.
__global__ __launch_bounds__(512, 2) void vq_fused(
    const float* __restrict__ U, const _Float16* __restrict__ Xh,
    const _Float16* __restrict__ CHT, const _Float16* __restrict__ CTT,
    const float* __restrict__ C2, const float* __restrict__ Tp,
    float* __restrict__ emb, float* __restrict__ ids,
    int* __restrict__ fixcnt, int* __restrict__ fixq) {
  __shared__ __align__(16) char smem[151552];
  const int tid = threadIdx.x;
  const int w = tid >> 6, l = tid & 63, l15 = l & 15, l4 = l >> 4;
  const int cs = w & 1, rs = w >> 1;
  const int row0 = blockIdx.x * BM;
  const float c1 = 1.4426950408889634f / Tp[0];
  const char* CHTc = (const char*)CHT;
  const char* CTTc = (const char*)CTT;

  half8 xr[16];
  {
    const _Float16* xb = Xh + (size_t)(row0 + rs*16 + l15) * DIM + l4 * 8;
#pragma unroll
    for (int kc = 0; kc < 16; ++kc) xr[kc] = *(const half8*)(xb + kc * 32);
  }

  const int sx = l15 & 7;
  const int qkb0 = ((cs*2 + 0) * 16 + l15) * 1024;
  const int qkb1 = ((cs*2 + 1) * 16 + l15) * 1024;
  const int prow = rs*16 + l15;
  int ctd[4];
#pragma unroll
  for (int dt = 0; dt < 4; ++dt) ctd[dt] = (w*4 + dt) * 16 + l15;

  const float* ub  = U + (size_t)(row0 + rs*16 + l15) * KC + cs*32 + l4*4;
  const float* c2p = C2 + cs*32 + l4*4;

  // prefetch: U two tiles ahead (static slots), c2 one ahead
  f32x4 uu0[2], uu1[2], c2pre[2];
  uu0[0] = ntload4(ub);        uu0[1] = ntload4(ub + 16);
  uu1[0] = ntload4(ub + 64);   uu1[1] = ntload4(ub + 80);
  c2pre[0] = *(const f32x4*)(c2p);      c2pre[1] = *(const f32x4*)(c2p + 16);

  // stage tile 0
  {
    const char* g = CHTc + (size_t)tid * 16;
    char* lb = smem + (size_t)tid * 16;
#pragma unroll
    for (int r = 0; r < 8; ++r) gload16(g + r * 8192, lb + r * 8192);
  }

  f32x4 O[4][4];
#pragma unroll
  for (int a = 0; a < 4; ++a)
#pragma unroll
    for (int b = 0; b < 4; ++b) { O[a][b][0]=0.f; O[a][b][1]=0.f; O[a][b][2]=0.f; O[a][b][3]=0.f; }
  half8 ctf[4][2];
  float mO[4] = {-3e38f, -3e38f, -3e38f, -3e38f};
  float m_own = -3e38f, l_run = 0.f;
  float v1 = -3e38f, v2 = -3e38f; int i1 = 0, i2 = 0;

  __syncthreads();   // tile 0 staged

#define BODY(T_, PH_)                                                           \
  {                                                                             \
    const int t = (T_);                                                         \
    /* 1. stage next tile (drains at this tile's barrier) */                    \
    if (t < NT - 1) {                                                           \
      const char* g = CHTc + ((size_t)(t + 1) << 16) + (size_t)tid * 16;        \
      char* lb = smem + ((1 - (PH_)) << 16) + (size_t)tid * 16;                 \
      _Pragma("unroll")                                                         \
      for (int r = 0; r < 8; ++r) gload16(g + r * 8192, lb + r * 8192);         \
    }                                                                           \
    /* 2. QK from LDS (staged two barriers ago, guaranteed complete) */         \
    const char* chc = smem + ((PH_) << 16);                                     \
    f32x4 a0 = {0.f,0.f,0.f,0.f}, a1 = {0.f,0.f,0.f,0.f};                       \
    _Pragma("unroll")                                                           \
    for (int kc = 0; kc < 16; ++kc) {                                           \
      const int uoff = ((kc * 4 + l4) ^ sx) << 4;                               \
      half8 A0 = *(const half8*)(chc + qkb0 + uoff);                            \
      half8 A1 = *(const half8*)(chc + qkb1 + uoff);                            \
      a0 = MFMA(A0, xr[kc], a0);                                                \
      a1 = MFMA(A1, xr[kc], a1);                                                \
    }                                                                           \
    /* 3. scores, top2, gumbel */                                               \
    float zz[2][4]; float mw = -3e38f;                                          \
    _Pragma("unroll")                                                           \
    for (int ct = 0; ct < 2; ++ct) {                                            \
      const int cbase = t*64 + (cs*2 + ct)*16 + l4*4;                           \
      const f32x4 av = ct ? a1 : a0;                                            \
      const f32x4 uv = ct ? uu##PH_[1] : uu##PH_[0];                            \
      _Pragma("unroll")                                                         \
      for (int r = 0; r < 4; ++r) {                                             \
        float s = av[r] - c2pre[ct][r];                                         \
        if (s > v1) { v2 = v1; i2 = i1; v1 = s; i1 = cbase + r; }               \
        else if (s > v2) { v2 = s; i2 = cbase + r; }                            \
        float li = flog2(uv[r] + 1e-10f);                                       \
        float y  = fmaf(li, -LN2, 1e-10f);                                      \
        float gb = flog2(y) * (-LN2);                                           \
        float z  = (s + gb) * c1;                                               \
        zz[ct][r] = z;                                                          \
        mw = fmaxf(mw, z);                                                      \
      }                                                                         \
    }                                                                           \
    mw = fmaxf(mw, __shfl_xor(mw, 16, 64));                                     \
    mw = fmaxf(mw, __shfl_xor(mw, 32, 64));                                     \
    {                                                                           \
      float* mt_ = (float*)(smem + 147456 + (PH_) * 512);                       \
      if (l < 16) mt_[w * 16 + l] = mw;                                         \
    }                                                                           \
    __syncthreads();  /* THE barrier: mtab + staged tile + old prefetches */    \
    /* 4. alphas (defer-max THR) */                                             \
    float alphaO[4];                                                            \
    {                                                                           \
      const float* mt_ = (float*)(smem + 147456 + (PH_) * 512);                 \
      _Pragma("unroll")                                                         \
      for (int rt = 0; rt < 4; ++rt) {                                          \
        float m2 = fmaxf(mt_[(2*rt)*16 + l15], mt_[(2*rt + 1)*16 + l15]);       \
        float mo = mO[rt];                                                      \
        float mn = (m2 > mo + DEFER_THR) ? m2 : mo;                             \
        alphaO[rt] = fexp2(mo - mn);                                            \
        mO[rt] = mn;                                                            \
      }                                                                         \
      float m2 = fmaxf(mt_[(2*rs)*16 + l15], mt_[(2*rs + 1)*16 + l15]);         \
      float mn = (m2 > m_own + DEFER_THR) ? m2 : m_own;                         \
      l_run *= fexp2(m_own - mn);                                               \
      m_own = mn;                                                               \
    }                                                                           \
    /* 5. post-barrier prefetch: U(t+2), c2(t+1) — full-tile window */          \
    if (t < NT - 2) {                                                           \
      uu##PH_[0] = ntload4(ub + (size_t)(t + 2) * 64);                          \
      uu##PH_[1] = ntload4(ub + (size_t)(t + 2) * 64 + 16);                     \
    }                                                                           \
    if (t < NT - 1) {                                                           \
      c2pre[0] = *(const f32x4*)(c2p + (t + 1) * 64);                           \
      c2pre[1] = *(const f32x4*)(c2p + (t + 1) * 64 + 16);                      \
    }                                                                           \
    /* 6. p = exp2(z - m_own), swizzled dbuf write */                           \
    {                                                                           \
      char* pcur = smem + 131072 + ((PH_) << 13);                               \
      _Pragma("unroll")                                                         \
      for (int ct = 0; ct < 2; ++ct) {                                          \
        float p0 = fexp2(zz[ct][0] - m_own);                                    \
        float p1 = fexp2(zz[ct][1] - m_own);                                    \
        float p2 = fexp2(zz[ct][2] - m_own);                                    \
        float p3 = fexp2(zz[ct][3] - m_own);                                    \
        l_run += (p0 + p1) + (p2 + p3);                                         \
        const int u = (cs*2 + ct)*2 + (l4 >> 1);                                \
        union { _Float16 h[4]; uint2 q; } pk;                                   \
        pk.h[0] = (_Float16)p0; pk.h[1] = (_Float16)p1;                         \
        pk.h[2] = (_Float16)p2; pk.h[3] = (_Float16)p3;                         \
        *(uint2*)(pcur + prow*128 + ((u ^ sx) << 4) + ((l4 & 1) << 3)) = pk.q;  \
      }                                                                         \
    }                                                                           \
    /* 7. PV(t-1) with prefetched CT frags */                                   \
    if (t > 0) {                                                                \
      const char* pprev = smem + 131072 + ((1 - (PH_)) << 13);                  \
      _Pragma("unroll")                                                         \
      for (int kc = 0; kc < 2; ++kc) {                                          \
        half8 pf[4];                                                            \
        _Pragma("unroll")                                                       \
        for (int rt = 0; rt < 4; ++rt)                                          \
          pf[rt] = *(const half8*)(pprev + (rt*16 + l15)*128                    \
                                   + (((kc*4 + l4) ^ sx) << 4));                \
        _Pragma("unroll")                                                       \
        for (int dt = 0; dt < 4; ++dt)                                          \
          _Pragma("unroll")                                                     \
          for (int rt = 0; rt < 4; ++rt)                                        \
            O[dt][rt] = MFMA(ctf[dt][kc], pf[rt], O[dt][rt]);                   \
      }                                                                         \
    }                                                                           \
    /* 8. CT frags for PV(t) next body */                                       \
    _Pragma("unroll")                                                           \
    for (int dt = 0; dt < 4; ++dt)                                              \
      _Pragma("unroll")                                                         \
      for (int kc = 0; kc < 2; ++kc)                                            \
        ctf[dt][kc] = *(const half8*)(CTTc + ((size_t)t << 16)                  \
                                      + ctd[dt]*128 + (((kc*4 + l4) ^ sx) << 4)); \
    /* 9. O rescale (rare; after PV(t-1)) */                                    \
    _Pragma("unroll")                                                           \
    for (int rt = 0; rt < 4; ++rt) {                                            \
      if (__any(alphaO[rt] != 1.0f)) {                                          \
        const float a_ = alphaO[rt];                                            \
        _Pragma("unroll")                                                       \
        for (int dt = 0; dt < 4; ++dt) {                                        \
          O[dt][rt][0] *= a_; O[dt][rt][1] *= a_;                               \
          O[dt][rt][2] *= a_; O[dt][rt][3] *= a_;                               \
        }                                                                       \
      }                                                                         \
    }                                                                           \
  }

#pragma unroll 1
  for (int tt = 0; tt < NT; tt += 2) {
    BODY(tt, 0)
    BODY(tt + 1, 1)
  }
#undef BODY

  __syncthreads();   // other waves' p(NT-1) visible
  // final PV(NT-1)
  {
    const char* pprev = smem + 131072 + (1 << 13);
#pragma unroll
    for (int kc = 0; kc < 2; ++kc) {
      half8 pf[4];
#pragma unroll
      for (int rt = 0; rt < 4; ++rt)
        pf[rt] = *(const half8*)(pprev + (rt*16 + l15)*128 + (((kc*4 + l4) ^ sx) << 4));
#pragma unroll
      for (int dt = 0; dt < 4; ++dt)
#pragma unroll
        for (int rt = 0; rt < 4; ++rt)
          O[dt][rt] = MFMA(ctf[dt][kc], pf[rt], O[dt][rt]);
    }
  }

  // ================= epilogue =================
  float lt2 = l_run;
  lt2 += __shfl_xor(lt2, 16, 64);
  lt2 += __shfl_xor(lt2, 32, 64);
  {
    float bv1 = __shfl_xor(v1, 16, 64); int bi1 = __shfl_xor(i1, 16, 64);
    float bv2 = __shfl_xor(v2, 16, 64); int bi2 = __shfl_xor(i2, 16, 64);
    top2_merge(v1, i1, v2, i2, bv1, bi1, bv2, bi2);
    bv1 = __shfl_xor(v1, 32, 64); bi1 = __shfl_xor(i1, 32, 64);
    bv2 = __shfl_xor(v2, 32, 64); bi2 = __shfl_xor(i2, 32, 64);
    top2_merge(v1, i1, v2, i2, bv1, bi1, bv2, bi2);
  }
  float* ltab = (float*)(smem + 148480);           // [8][16]
  f32x4* atab = (f32x4*)(smem + 149504);           // [8][16] (v1,i1,v2,i2)
  if (l < 16) {
    ltab[w*16 + l] = lt2;
    f32x4 pk;
    pk[0] = v1; pk[1] = __int_as_float(i1); pk[2] = v2; pk[3] = __int_as_float(i2);
    atab[w*16 + l] = pk;
  }
  __syncthreads();

  float inv4[4];
#pragma unroll
  for (int rt = 0; rt < 4; ++rt)
    inv4[rt] = 1.0f / (ltab[(2*rt)*16 + l15] + ltab[(2*rt + 1)*16 + l15]);

  if (w == 0) {
    f32x4 A = atab[(2*(l >> 4))*16 + (l & 15)];
    f32x4 B = atab[(2*(l >> 4) + 1)*16 + (l & 15)];
    float V1 = A[0], V2 = A[2];
    int I1 = __float_as_int(A[1]), I2 = __float_as_int(A[3]);
    top2_merge(V1, I1, V2, I2, B[0], __float_as_int(B[1]), B[2], __float_as_int(B[3]));
    ids[row0 + l] = (float)I1;
    if (V1 - V2 <= MARGIN) {
      int qi = atomicAdd(fixcnt, 1);
      if (qi < QCAP) { fixq[qi*3] = row0 + l; fixq[qi*3 + 1] = I1; fixq[qi*3 + 2] = I2; }
    }
  }

  // staged, coalesced emb store (wave-private LDS slice in chA/p region)
  char* wbase = smem + w * 16384;
#pragma unroll
  for (int h = 0; h < 2; ++h) {
#pragma unroll
    for (int rtl = 0; rtl < 2; ++rtl) {
      const int rt = 2*h + rtl;
      const int lrow = rtl*16 + l15;
#pragma unroll
      for (int dt = 0; dt < 4; ++dt)
#pragma unroll
        for (int r = 0; r < 4; ++r) {
          const int dloc = dt*16 + l4*4 + r;
          *(float*)(wbase + (lrow*72 + dloc)*4) = O[dt][rt][r] * inv4[rt];
        }
    }
    __builtin_amdgcn_s_waitcnt(0);
#pragma unroll
    for (int ir = 0; ir < 8; ++ir) {
      const int lrow = ir*4 + l4;
      f32x4 vv = *(const f32x4*)(wbase + (lrow*72 + l15*4)*4);
      __builtin_nontemporal_store(vv,
          (f32x4*)(emb + (size_t)(row0 + h*32 + lrow)*DIM + w*64 + l15*4));
    }
  }
}

// exact rescoring of flagged near-ties (f64)
__global__ void vq_fixup(const float* __restrict__ X, const float* __restrict__ C,
                         const int* __restrict__ fixcnt, const int* __restrict__ fixq,
                         float* __restrict__ ids) {
  const int nw = (gridDim.x * blockDim.x) >> 6;
  const int gw = (blockIdx.x * blockDim.x + threadIdx.x) >> 6;
  const int l = threadIdx.x & 63;
  int cnt = *fixcnt; if (cnt > QCAP) cnt = QCAP;
  for (int q = gw; q < cnt; q += nw) {
    const int row = fixq[q*3], a = fixq[q*3 + 1], b = fixq[q*3 + 2];
    double da = 0, ca = 0, db = 0, cb = 0;
    for (int i = l; i < DIM; i += 64) {
      double xv = X[(size_t)row * DIM + i];
      double av = C[(size_t)a * DIM + i];
      double bv = C[(size_t)b * DIM + i];
      da += xv * av; ca += av * av;
      db += xv * bv; cb += bv * bv;
    }
#pragma unroll
    for (int o = 32; o; o >>= 1) {
      da += __shfl_down(da, o, 64); ca += __shfl_down(ca, o, 64);
      db += __shfl_down(db, o, 64); cb += __shfl_down(cb, o, 64);
    }
    if (l == 0) {
      double sa = 2.0 * da - ca, sb = 2.0 * db - cb;
      int win = (sb > sa || (sb == sa && b < a)) ? b : a;
      ids[row] = (float)win;
    }
  }
}

extern "C" void kernel_launch(void* const* d_in, const int* in_sizes, int n_in,
                              void* d_out, int out_size, void* d_ws, size_t ws_size,
                              hipStream_t stream) {
  (void)in_sizes; (void)n_in; (void)out_size; (void)ws_size;
  const float* x  = (const float*)d_in[0];
  const float* cb = (const float*)d_in[1];
  const float* u  = (const float*)d_in[2];
  const float* tp = (const float*)d_in[3];
  float* emb = (float*)d_out;
  float* ids = emb + (size_t)NROWS * DIM;

  char* ws = (char*)d_ws;
  int* fixcnt = (int*)ws;
  int* fixq = (int*)(ws + 256);
  size_t off = (256 + (size_t)QCAP * 12 + 511) & ~(size_t)511;
  _Float16* xh  = (_Float16*)(ws + off); off += (size_t)NROWS * DIM * 2;
  _Float16* cht = (_Float16*)(ws + off); off += (size_t)KC * DIM * 2;
  _Float16* ctt = (_Float16*)(ws + off); off += (size_t)DIM * KC * 2;
  float* c2 = (float*)(ws + off);

  hipMemsetAsync(fixcnt, 0, 4, stream);
  prep_x  <<<(NROWS * DIM) / 1024, 256, 0, stream>>>(x, xh);
  prep_cht<<<(KC * 64) / 256, 256, 0, stream>>>(cb, cht);
  prep_ctt<<<(KC / 64) * (DIM / 64), 256, 0, stream>>>(cb, ctt);
  prep_c2 <<<KC / 4, 256, 0, stream>>>(cb, c2);
  vq_fused<<<NROWS / BM, 512, 0, stream>>>(u, xh, cht, ctt, c2, tp, emb, ids, fixcnt, fixq);
  vq_fixup<<<32, 256, 0, stream>>>(x, cb, fixcnt, fixq, ids);
}

// Round 6
// 606.134 us; speedup vs baseline: 2.5697x; 2.5697x over previous
//
#include <hip/hip_runtime.h>

#define NROWS 16384
#define DIM   512
#define KC    8192
#define BM    32
#define KTILE 32
#define NT    256            // KC / KTILE
#define QCAP  32768
#define MARGIN 0.05f
#define DEFER_THR 8.0f
#define LN2   0.69314718055994531f

typedef _Float16 half8  __attribute__((ext_vector_type(8)));
typedef float    f32x4  __attribute__((ext_vector_type(4)));
typedef unsigned int u32;

#define MFMA(a,b,c) __builtin_amdgcn_mfma_f32_16x16x32_f16(a,b,c,0,0,0)

__device__ __forceinline__ float flog2(float x){ return __builtin_amdgcn_logf(x); }
__device__ __forceinline__ float fexp2(float x){ return __builtin_amdgcn_exp2f(x); }
__device__ __forceinline__ f32x4 ntload4(const float* p){
  return __builtin_nontemporal_load((const f32x4*)p);
}
__device__ __forceinline__ void gload16(const void* g, void* l){
  __builtin_amdgcn_global_load_lds(
      (const __attribute__((address_space(1))) u32*)g,
      (__attribute__((address_space(3))) u32*)l, 16, 0, 0);
}

__device__ __forceinline__ void top2_merge(float& v1, int& i1, float& v2, int& i2,
                                           float bv1, int bi1, float bv2, int bi2) {
  bool takeB = (bv1 > v1) || (bv1 == v1 && bi1 < i1);
  float nv1 = takeB ? bv1 : v1; int ni1 = takeB ? bi1 : i1;
  float cv  = takeB ? v1  : bv1; int ci = takeB ? i1  : bi1;
  float ov2 = takeB ? bv2 : v2;  int oi = takeB ? bi2 : i2;
  bool cb = (cv > ov2) || (cv == ov2 && ci < oi);
  v2 = cb ? cv : ov2; i2 = cb ? ci : oi;
  v1 = nv1; i1 = ni1;
}

// ---------------- prep kernels ----------------
__global__ void prep_x(const float* __restrict__ x, _Float16* __restrict__ xh) {
  size_t i = (size_t)(blockIdx.x * blockDim.x + threadIdx.x) * 4;
  f32x4 v = *(const f32x4*)(x + i);
  _Float16 h4[4];
  h4[0] = (_Float16)(2.0f * v[0]); h4[1] = (_Float16)(2.0f * v[1]);
  h4[2] = (_Float16)(2.0f * v[2]); h4[3] = (_Float16)(2.0f * v[3]);
  *(uint2*)(xh + i) = *(uint2*)h4;
}

// codebook, tiled [256 t][32 c][512 d] f16, 16B-unit swizzled: u -> u^(c&7)
__global__ void prep_cht(const float* __restrict__ c, _Float16* __restrict__ cht) {
  const int gid = blockIdx.x * 256 + threadIdx.x;     // one 16B unit each
  const int code = gid >> 6, u = gid & 63;
  f32x4 v0 = *(const f32x4*)(c + (size_t)code * DIM + u * 8);
  f32x4 v1 = *(const f32x4*)(c + (size_t)code * DIM + u * 8 + 4);
  half8 h;
#pragma unroll
  for (int q = 0; q < 4; ++q) { h[q] = (_Float16)v0[q]; h[4+q] = (_Float16)v1[q]; }
  const int t = code >> 5, cc = code & 31;
  *(half8*)((char*)cht + (size_t)t * 32768 + cc * 1024 + ((u ^ (cc & 7)) << 4)) = h;
}

// codebook^T, tiled [256 t][512 d][32 k] f16, unit (k/8) -> u^(d&3)
__global__ void prep_ctt(const float* __restrict__ c, _Float16* __restrict__ ctt) {
  __shared__ _Float16 lt[64][72];
  const int kb = (blockIdx.x >> 3) * 64;
  const int db = (blockIdx.x & 7) * 64;
  {
    const int r = threadIdx.x >> 2, c4 = threadIdx.x & 3;
#pragma unroll
    for (int j = 0; j < 4; ++j) {
      f32x4 v = *(const f32x4*)(c + (size_t)(kb + r) * DIM + db + c4 * 16 + j * 4);
#pragma unroll
      for (int q = 0; q < 4; ++q) lt[r][c4 * 16 + j * 4 + q] = (_Float16)v[q];
    }
  }
  __syncthreads();
  {
    const int d = threadIdx.x >> 2, ks = threadIdx.x & 3;
    half8 o0, o1;
#pragma unroll
    for (int j = 0; j < 8; ++j) { o0[j] = lt[ks*16 + j][d]; o1[j] = lt[ks*16 + 8 + j][d]; }
    const int dg = db + d;
    const int t = (kb >> 5) + (ks >> 1);
    const int u0 = (ks & 1) * 2;
    char* base = (char*)ctt + (size_t)t * 32768 + (size_t)dg * 64;
    *(half8*)(base + ((u0       ^ (dg & 3)) << 4)) = o0;
    *(half8*)(base + (((u0 + 1) ^ (dg & 3)) << 4)) = o1;
  }
}

__global__ void prep_c2(const float* __restrict__ c, float* __restrict__ c2) {
  const int w = threadIdx.x >> 6, l = threadIdx.x & 63;
  const int code = blockIdx.x * 4 + w;
  double s = 0.0;
  for (int i = l; i < DIM; i += 64) { double v = c[(size_t)code * DIM + i]; s += v * v; }
#pragma unroll
  for (int o = 32; o; o >>= 1) s += __shfl_down(s, o, 64);
  if (l == 0) c2[code] = (float)s;
}

// ---------------- main fused kernel ----------------
// grid 512 x 256 thr (2 blocks/CU -> decorrelated barrier domains). BM=32 rows,
// KTILE=32 codes, 256 steps. R4's proven 2-barrier schedule, re-parameterized.
// Waves: cs=w&1 (16-code half), rs=w>>1 (16-row half). PV: 128 d per wave, all rows.
// LDS 71680 B: [0,64K) chA dbuf | [64K,68K) p dbuf | tables at 69632+.
__global__ __launch_bounds__(256, 2) void vq_fused(
    const float* __restrict__ U, const _Float16* __restrict__ Xh,
    const _Float16* __restrict__ CHT, const _Float16* __restrict__ CTT,
    const float* __restrict__ C2, const float* __restrict__ Tp,
    float* __restrict__ emb, float* __restrict__ ids,
    int* __restrict__ fixcnt, int* __restrict__ fixq) {
  __shared__ __align__(16) char smem[71680];
  const int tid = threadIdx.x;
  const int w = tid >> 6, l = tid & 63, l15 = l & 15, l4 = l >> 4;
  const int cs = w & 1, rs = w >> 1;
  const int row0 = blockIdx.x * BM;
  const float c1 = 1.4426950408889634f / Tp[0];   // log2e / T
  const char* CHTc = (const char*)CHT;
  const char* CTTc = (const char*)CTT;

  // x rows resident in registers: row rs*16+l15, all 512 d
  half8 xr[16];
  {
    const _Float16* xb = Xh + (size_t)(row0 + rs*16 + l15) * DIM + l4 * 8;
#pragma unroll
    for (int kc = 0; kc < 16; ++kc) xr[kc] = *(const half8*)(xb + kc * 32);
  }

  const int sxq = l15 & 7;                     // chA row-xor (64 units/row)
  const int sxp = (l15 ^ (l15 >> 2)) & 3;      // p/CTT row-xor (4 units/row)
  const int qkb = (cs*16 + l15) * 1024;        // this lane's QK A-row base
  const int prow = rs*16 + l15;                // p row this lane writes

  const float* ub  = U  + (size_t)(row0 + prow) * KC + cs*16 + l4*4;
  const float* c2p = C2 + cs*16 + l4*4;

  f32x4 upre  = ntload4(ub);
  f32x4 c2pre = *(const f32x4*)(c2p);

  // stage tile 0 (32 KB, coalesced; LDS dest wave-uniform base)
  {
    const char* g = CHTc + (size_t)(w*64 + l) * 16;
    char* lb = smem + w * 1024;
#pragma unroll
    for (int r = 0; r < 8; ++r) gload16(g + r * 4096, lb + r * 4096);
  }

  f32x4 O[8][2];   // [dt: d=w*128+dt*16][rt: row half]
#pragma unroll
  for (int a = 0; a < 8; ++a)
#pragma unroll
    for (int b = 0; b < 2; ++b) { O[a][b][0]=0.f; O[a][b][1]=0.f; O[a][b][2]=0.f; O[a][b][3]=0.f; }
  half8 ctf[8];
  float mO[2] = {-3e38f, -3e38f};              // per-row-half running maxes
  float l_run = 0.f;
  float v1 = -3e38f, v2 = -3e38f; int i1 = 0, i2 = 0;
  float* mtab = (float*)(smem + 69632);        // [4][16]

  __syncthreads();   // tile 0 staged

#pragma unroll 1
  for (int t = 0; t < NT; ++t) {
    const char* chc = smem + ((t & 1) << 15);

    // 1. stage next code-tile
    if (t < NT - 1) {
      const char* g = CHTc + ((size_t)(t + 1)) * 32768 + (size_t)(w*64 + l) * 16;
      char* lb = smem + (((t + 1) & 1) << 15) + w * 1024;
#pragma unroll
      for (int r = 0; r < 8; ++r) gload16(g + r * 4096, lb + r * 4096);
    }

    // 2. QK: S^T tile [16 codes x 16 rows], A from LDS (swizzled), B from regs
    f32x4 a0 = {0.f, 0.f, 0.f, 0.f};
#pragma unroll
    for (int kc = 0; kc < 16; ++kc) {
      half8 A0 = *(const half8*)(chc + qkb + (((kc*4 + l4) ^ sxq) << 4));
      a0 = MFMA(A0, xr[kc], a0);
    }

    // 3. scores, top2, gumbel, z
    f32x4 zz; float mw = -3e38f;
    {
      const int cbase = t*32 + cs*16 + l4*4;
#pragma unroll
      for (int r = 0; r < 4; ++r) {
        float s = a0[r] - c2pre[r];                 // 2 x.c - |c|^2
        if (s > v1) { v2 = v1; i2 = i1; v1 = s; i1 = cbase + r; }
        else if (s > v2) { v2 = s; i2 = cbase + r; }
        float li = flog2(upre[r] + 1e-10f);
        float y  = fmaf(li, -LN2, 1e-10f);
        float g  = flog2(y) * (-LN2);
        float z  = (s + g) * c1;
        zz[r] = z;
        mw = fmaxf(mw, z);
      }
    }
    mw = fmaxf(mw, __shfl_xor(mw, 16, 64));
    mw = fmaxf(mw, __shfl_xor(mw, 32, 64));
    if (l < 16) mtab[w*16 + l] = mw;
    __syncthreads();                       // B1: mtab + staged tile visible

    // 4. per-row-half alphas, defer-max THR (T13); m_own == mO[rs]
    float alphaO[2];
#pragma unroll
    for (int rt = 0; rt < 2; ++rt) {
      float mt = fmaxf(mtab[(2*rt)*16 + l15], mtab[(2*rt + 1)*16 + l15]);
      float mo = mO[rt];
      float mn = (mt > mo + DEFER_THR) ? mt : mo;
      alphaO[rt] = fexp2(mo - mn);
      mO[rt] = mn;
    }
    const float m_own = rs ? mO[1] : mO[0];
    const float a_own = rs ? alphaO[1] : alphaO[0];

    // 4.5 prefetch U/c2 for t+1 (post-B1: drains at B2, after PV)
    if (t < NT - 1) {
      upre  = ntload4(ub + (size_t)(t + 1) * 32);
      c2pre = *(const f32x4*)(c2p + (t + 1) * 32);
    }

    // 5. p = exp2(z - m_own) (bounded by 2^THR), swizzled dbuf write
    {
      char* pcur = smem + 65536 + ((t & 1) << 11);
      float p0 = fexp2(zz[0] - m_own);
      float p1 = fexp2(zz[1] - m_own);
      float p2 = fexp2(zz[2] - m_own);
      float p3 = fexp2(zz[3] - m_own);
      l_run = l_run * a_own + ((p0 + p1) + (p2 + p3));
      const int u = cs*2 + (l4 >> 1);
      union { _Float16 h[4]; uint2 q; } pk;
      pk.h[0] = (_Float16)p0; pk.h[1] = (_Float16)p1;
      pk.h[2] = (_Float16)p2; pk.h[3] = (_Float16)p3;
      *(uint2*)(pcur + prow*64 + ((u ^ sxp) << 4) + ((l4 & 1) << 3)) = pk.q;
    }

    // 6. PV(t-1): O += CT(t-1) * P^T(t-1)  (CT frags already in regs)
    if (t > 0) {
      const char* pprev = smem + 65536 + (((t - 1) & 1) << 11);
      half8 pf0 = *(const half8*)(pprev + l15*64        + ((l4 ^ sxp) << 4));
      half8 pf1 = *(const half8*)(pprev + (16 + l15)*64 + ((l4 ^ sxp) << 4));
#pragma unroll
      for (int dt = 0; dt < 8; ++dt) {
        O[dt][0] = MFMA(ctf[dt], pf0, O[dt][0]);
        O[dt][1] = MFMA(ctf[dt], pf1, O[dt][1]);
      }
    }

    // 7. CT frags for PV(t) (L2-hot pre-tiled layout)
#pragma unroll
    for (int dt = 0; dt < 8; ++dt)
      ctf[dt] = *(const half8*)(CTTc + (size_t)t * 32768
                                + (size_t)(w*128 + dt*16 + l15) * 64
                                + ((l4 ^ (l15 & 3)) << 4));

    // 8. O rescale (rare with defer-max; after PV(t-1))
#pragma unroll
    for (int rt = 0; rt < 2; ++rt) {
      if (__any(alphaO[rt] != 1.0f)) {
        const float a_ = alphaO[rt];
#pragma unroll
        for (int dt = 0; dt < 8; ++dt) {
          O[dt][rt][0] *= a_; O[dt][rt][1] *= a_;
          O[dt][rt][2] *= a_; O[dt][rt][3] *= a_;
        }
      }
    }

    __syncthreads();                       // B2: stage(t+1) + p(t) visible
  }

  // final PV(NT-1)
  {
    const char* pprev = smem + 65536 + (((NT - 1) & 1) << 11);
    half8 pf0 = *(const half8*)(pprev + l15*64        + ((l4 ^ sxp) << 4));
    half8 pf1 = *(const half8*)(pprev + (16 + l15)*64 + ((l4 ^ sxp) << 4));
#pragma unroll
    for (int dt = 0; dt < 8; ++dt) {
      O[dt][0] = MFMA(ctf[dt], pf0, O[dt][0]);
      O[dt][1] = MFMA(ctf[dt], pf1, O[dt][1]);
    }
  }

  // ================= epilogue =================
  float lt2 = l_run;
  lt2 += __shfl_xor(lt2, 16, 64);
  lt2 += __shfl_xor(lt2, 32, 64);
  {
    float bv1 = __shfl_xor(v1, 16, 64); int bi1 = __shfl_xor(i1, 16, 64);
    float bv2 = __shfl_xor(v2, 16, 64); int bi2 = __shfl_xor(i2, 16, 64);
    top2_merge(v1, i1, v2, i2, bv1, bi1, bv2, bi2);
    bv1 = __shfl_xor(v1, 32, 64); bi1 = __shfl_xor(i1, 32, 64);
    bv2 = __shfl_xor(v2, 32, 64); bi2 = __shfl_xor(i2, 32, 64);
    top2_merge(v1, i1, v2, i2, bv1, bi1, bv2, bi2);
  }
  float* ltab = (float*)(smem + 69888);            // [4][16]
  f32x4* atab = (f32x4*)(smem + 70144);            // [4][16] (v1,i1,v2,i2)
  if (l < 16) {
    ltab[w*16 + l] = lt2;
    f32x4 pk;
    pk[0] = v1; pk[1] = __int_as_float(i1); pk[2] = v2; pk[3] = __int_as_float(i2);
    atab[w*16 + l] = pk;
  }
  __syncthreads();

  const float invr0 = 1.0f / (ltab[l15] + ltab[16 + l15]);
  const float invr1 = 1.0f / (ltab[32 + l15] + ltab[48 + l15]);

  if (w == 0 && l < 32) {   // final per-row argmax + near-tie flagging
    const int rt = l >> 4, r15 = l & 15;
    f32x4 A = atab[(2*rt)*16 + r15];
    f32x4 B = atab[(2*rt + 1)*16 + r15];
    float V1 = A[0], V2 = A[2];
    int I1 = __float_as_int(A[1]), I2 = __float_as_int(A[3]);
    top2_merge(V1, I1, V2, I2, B[0], __float_as_int(B[1]), B[2], __float_as_int(B[3]));
    ids[row0 + l] = (float)I1;
    if (V1 - V2 <= MARGIN) {
      int qi = atomicAdd(fixcnt, 1);
      if (qi < QCAP) { fixq[qi*3] = row0 + l; fixq[qi*3 + 1] = I1; fixq[qi*3 + 2] = I2; }
    }
  }

  // staged, coalesced, non-temporal emb store: two passes of 16 rows
  float* stagef = (float*)smem;   // [16][520] f32 (reuses chA region)
#pragma unroll
  for (int h = 0; h < 2; ++h) {
    __syncthreads();
    const float iv = h ? invr1 : invr0;
#pragma unroll
    for (int dt = 0; dt < 8; ++dt) {
      f32x4 v = O[dt][h];
      v[0] *= iv; v[1] *= iv; v[2] *= iv; v[3] *= iv;
      *(f32x4*)(stagef + l15*520 + w*128 + dt*16 + l4*4) = v;
    }
    __syncthreads();
#pragma unroll
    for (int q = 0; q < 8; ++q) {
      const int c = q*256 + tid;
      const int r_ = c >> 7, col = c & 127;
      f32x4 v = *(const f32x4*)(stagef + r_*520 + col*4);
      __builtin_nontemporal_store(v,
          (f32x4*)(emb + (size_t)(row0 + h*16 + r_)*DIM + col*4));
    }
  }
}

// exact rescoring of flagged near-ties (f64)
__global__ void vq_fixup(const float* __restrict__ X, const float* __restrict__ C,
                         const int* __restrict__ fixcnt, const int* __restrict__ fixq,
                         float* __restrict__ ids) {
  const int nw = (gridDim.x * blockDim.x) >> 6;
  const int gw = (blockIdx.x * blockDim.x + threadIdx.x) >> 6;
  const int l = threadIdx.x & 63;
  int cnt = *fixcnt; if (cnt > QCAP) cnt = QCAP;
  for (int q = gw; q < cnt; q += nw) {
    const int row = fixq[q*3], a = fixq[q*3 + 1], b = fixq[q*3 + 2];
    double da = 0, ca = 0, db = 0, cb = 0;
    for (int i = l; i < DIM; i += 64) {
      double xv = X[(size_t)row * DIM + i];
      double av = C[(size_t)a * DIM + i];
      double bv = C[(size_t)b * DIM + i];
      da += xv * av; ca += av * av;
      db += xv * bv; cb += bv * bv;
    }
#pragma unroll
    for (int o = 32; o; o >>= 1) {
      da += __shfl_down(da, o, 64); ca += __shfl_down(ca, o, 64);
      db += __shfl_down(db, o, 64); cb += __shfl_down(cb, o, 64);
    }
    if (l == 0) {
      double sa = 2.0 * da - ca, sb = 2.0 * db - cb;
      int win = (sb > sa || (sb == sa && b < a)) ? b : a;
      ids[row] = (float)win;
    }
  }
}

extern "C" void kernel_launch(void* const* d_in, const int* in_sizes, int n_in,
                              void* d_out, int out_size, void* d_ws, size_t ws_size,
                              hipStream_t stream) {
  (void)in_sizes; (void)n_in; (void)out_size; (void)ws_size;
  const float* x  = (const float*)d_in[0];
  const float* cb = (const float*)d_in[1];
  const float* u  = (const float*)d_in[2];
  const float* tp = (const float*)d_in[3];
  float* emb = (float*)d_out;
  float* ids = emb + (size_t)NROWS * DIM;

  char* ws = (char*)d_ws;
  int* fixcnt = (int*)ws;
  int* fixq = (int*)(ws + 256);
  size_t off = (256 + (size_t)QCAP * 12 + 511) & ~(size_t)511;
  _Float16* xh  = (_Float16*)(ws + off); off += (size_t)NROWS * DIM * 2;
  _Float16* cht = (_Float16*)(ws + off); off += (size_t)KC * DIM * 2;
  _Float16* ctt = (_Float16*)(ws + off); off += (size_t)DIM * KC * 2;
  float* c2 = (float*)(ws + off);

  hipMemsetAsync(fixcnt, 0, 4, stream);
  prep_x  <<<(NROWS * DIM) / 1024, 256, 0, stream>>>(x, xh);
  prep_cht<<<(KC * 64) / 256, 256, 0, stream>>>(cb, cht);
  prep_ctt<<<(KC / 64) * (DIM / 64), 256, 0, stream>>>(cb, ctt);
  prep_c2 <<<KC / 4, 256, 0, stream>>>(cb, c2);
  vq_fused<<<NROWS / BM, 256, 0, stream>>>(u, xh, cht, ctt, c2, tp, emb, ids, fixcnt, fixq);
  vq_fixup<<<32, 256, 0, stream>>>(x, cb, fixcnt, fixq, ids);
}